// Round 9
// baseline (155.339 us; speedup 1.0000x reference)
//
#include <hip/hip_runtime.h>
#include <hip/hip_bf16.h>
#include <math.h>

#define D 256
#define D_SEQ 1280
#define D_HEAD 48
#define N_HEAD 8
#define HDH 384        // N_HEAD * D_HEAD
#define N_NODE 2048
#define B_GRAPH 8
#define S_LEN 1024
#define LN_EPS 1e-5f
#define QSCALE (0.14433756729740643f * 1.4426950408889634f)  // 1/sqrt(48)*log2(e)
#define KVN 768
#define QGN 768
#define QROWS (N_NODE + 16)              // padded Q rows per head
#define TPG 40         // max 16-node tiles per graph
#define NWL (TPG * 8)  // strided worklist: wl[i*8+b]
#define PAD_T 164864

typedef unsigned short u16;
typedef __attribute__((ext_vector_type(8))) short short8;
typedef __attribute__((ext_vector_type(4))) short short4v;
typedef __attribute__((ext_vector_type(4))) unsigned short ushort4v;
typedef __attribute__((ext_vector_type(4))) float floatx4;

__device__ __forceinline__ u16 f2bf(float f) {
    unsigned int x = __float_as_uint(f);
    x += 0x7fff + ((x >> 16) & 1);      // RNE to bf16
    return (u16)(x >> 16);
}

// async 16B-per-lane global->LDS DMA (wave-uniform LDS base + lane*16B)
__device__ __forceinline__ void load_lds16(const u16* g, u16* lds) {
    __builtin_amdgcn_global_load_lds(
        (const __attribute__((address_space(1))) unsigned int*)g,
        (__attribute__((address_space(3))) unsigned int*)lds, 16, 0, 0);
}

// ---------------------------------------------------------------------------
// prep: unchanged from R7/R8.
// ---------------------------------------------------------------------------
__global__ __launch_bounds__(256)
void prep(const float* __restrict__ emb, u16* __restrict__ embb,
          const float* __restrict__ node, const float* __restrict__ ln_g,
          const float* __restrict__ ln_b, u16* __restrict__ yb,
          const float* __restrict__ Wk, const float* __restrict__ Wv,
          const float* __restrict__ Wq, const float* __restrict__ Wg,
          const float* __restrict__ Wback,
          u16* __restrict__ WT, u16* __restrict__ WT2, u16* __restrict__ WbT,
          const int* __restrict__ batch, const int* __restrict__ mask,
          int* __restrict__ ranges, int* __restrict__ wl,
          int* __restrict__ kvwl, int* __restrict__ scnt,
          u16* __restrict__ Kp, u16* __restrict__ Qb) {
    const int bx = blockIdx.x;
    const int tid = threadIdx.x;
    if (bx < 1024) {
        // ---- mask-compacted conversion: 8 rows/block, 32 lanes/row ----
        const int b = bx >> 7, chunk = bx & 127;
        __shared__ unsigned long long words[16];
        __shared__ int wpre[17];
        #pragma unroll
        for (int c = 0; c < 4; ++c) {
            const int s = c * 256 + tid;
            const unsigned long long bal = __ballot(mask[b * S_LEN + s] != 0);
            if ((tid & 63) == 0) words[c * 4 + (tid >> 6)] = bal;
        }
        __syncthreads();
        if (tid == 0) {
            int a = 0;
            #pragma unroll
            for (int w = 0; w < 16; ++w) { wpre[w] = a; a += __popcll(words[w]); }
            wpre[16] = a;
        }
        __syncthreads();
        const int cnt = wpre[16];
        const int ce = (cnt + 127) & ~127;        // ceil128
        const int r = chunk * 8 + (tid >> 5);     // orig row
        const int sub = tid & 31;
        const unsigned long long w = words[r >> 6];
        const bool on = (w >> (r & 63)) & 1ull;
        if (on) {
            const int rank = wpre[r >> 6] +
                __popcll(w & ((1ull << (r & 63)) - 1ull));
            const float* src = &emb[((size_t)b * S_LEN + r) * D_SEQ];
            u16* dst = &embb[((size_t)b * S_LEN + rank) * D_SEQ];
            #pragma unroll
            for (int it = 0; it < 5; ++it) {
                const int off = it * 256 + sub * 8;
                const float4 a = *(const float4*)&src[off];
                const float4 b4 = *(const float4*)&src[off + 4];
                union { u16 u[8]; int4 v; } p;
                p.u[0]=f2bf(a.x); p.u[1]=f2bf(a.y); p.u[2]=f2bf(a.z); p.u[3]=f2bf(a.w);
                p.u[4]=f2bf(b4.x); p.u[5]=f2bf(b4.y); p.u[6]=f2bf(b4.z); p.u[7]=f2bf(b4.w);
                *(int4*)&dst[off] = p.v;
            }
        }
        const int c2 = chunk * 8 + (tid >> 5);
        if (c2 >= cnt && c2 < ce) {
            u16* dst = &embb[((size_t)b * S_LEN + c2) * D_SEQ];
            const int4 z = {0, 0, 0, 0};
            #pragma unroll
            for (int it = 0; it < 5; ++it)
                *(int4*)&dst[it * 256 + sub * 8] = z;
        }
        return;
    }
    if (bx < 3072) {
        const int n = bx - 1024, t = tid;
        float x = node[n * D + t];
        float s = x, sq = x * x;
        #pragma unroll
        for (int o = 32; o > 0; o >>= 1) {
            s  += __shfl_down(s, o);
            sq += __shfl_down(sq, o);
        }
        __shared__ float ss[4], sqs[4];
        if ((t & 63) == 0) { ss[t >> 6] = s; sqs[t >> 6] = sq; }
        __syncthreads();
        float S  = ss[0] + ss[1] + ss[2] + ss[3];
        float SQ = sqs[0] + sqs[1] + sqs[2] + sqs[3];
        float mu  = S * (1.f / D);
        float var = SQ * (1.f / D) - mu * mu;
        float inv = rsqrtf(var + LN_EPS);
        yb[n * D + t] = f2bf((x - mu) * inv * ln_g[t] + ln_b[t]);
        return;
    }
    if (bx < 4320) {
        int u = bx - 3072;
        const float* W; u16* WTo; int K, kx, ny, Ncols;
        if (u < 480)      { W = Wk;    WTo = WT;                       K = D_SEQ; Ncols = HDH; kx = u % 40; ny = u / 40; }
        else if (u < 960) { u -= 480;  W = Wv; WTo = WT + (size_t)HDH * D_SEQ; K = D_SEQ; Ncols = HDH; kx = u % 40; ny = u / 40; }
        else if (u < 1056){ u -= 960;  W = Wq; WTo = WT2;              K = D;   Ncols = HDH; kx = u % 8;  ny = u / 8; }
        else if (u < 1152){ u -= 1056; W = Wg; WTo = WT2 + (size_t)HDH * D; K = D; Ncols = HDH; kx = u % 8; ny = u / 8; }
        else              { u -= 1152; W = Wback; WTo = WbT;           K = HDH; Ncols = D;   kx = u % 12; ny = u / 12; }
        const int k0 = kx * 32, n0 = ny * 32;
        __shared__ float tile[32][33];
        const int tx = tid & 31, ty = tid >> 5;
        #pragma unroll
        for (int i = 0; i < 32; i += 8)
            tile[ty + i][tx] = W[(size_t)(k0 + ty + i) * Ncols + n0 + tx];
        __syncthreads();
        #pragma unroll
        for (int i = 0; i < 32; i += 8)
            WTo[(size_t)(n0 + ty + i) * K + k0 + tx] = f2bf(tile[tx][ty + i]);
        return;
    }
    if (bx == 4320) {
        const int t = tid;
        __shared__ int msum[8][32];
        __shared__ int mcnt[8];
        const int g = t >> 5, ii = t & 31;
        int p = 0;
        #pragma unroll
        for (int k = 0; k < 32; ++k) p += mask[g * S_LEN + k * 32 + ii];
        msum[g][ii] = p;
        if (t <= B_GRAPH) {
            int lo = 0, hi = N_NODE;
            while (lo < hi) {
                int mid = (lo + hi) >> 1;
                if (batch[mid] < t) lo = mid + 1; else hi = mid;
            }
            ranges[t] = lo;
        }
        __syncthreads();
        if (t < 8) {
            int s = 0;
            #pragma unroll
            for (int k = 0; k < 32; ++k) s += msum[t][k];
            mcnt[t] = s;
            scnt[t] = s;
        }
        __syncthreads();
        if (t < B_GRAPH) {
            const int s = ranges[t];
            const int ntile = (ranges[t + 1] - s + 15) >> 4;
            for (int i = 0; i < TPG; ++i)
                wl[i * 8 + t] = (i < ntile) ? ((t << 16) | (s + i * 16)) : -1;
            const int tc = (mcnt[t] + 127) >> 7;   // KV m-tiles for this graph
            for (int i = 0; i < 8; ++i)
                kvwl[i * 8 + t] = (i < tc) ? (t * S_LEN + i * 128) : -1;
        }
        return;
    }
    const int t = (bx - 4321) * 256 + tid;
    const int4 z = {0, 0, 0, 0};
    if (t < 131072) {
        const int row = t >> 1, half = t & 1;
        *(int4*)&Kp[(size_t)row * 64 + 48 + half * 8] = z;
    } else if (t < 164096) {
        const int u = t - 131072;
        const int row = u >> 1, half = u & 1;
        *(int4*)&Qb[(size_t)row * 64 + 48 + half * 8] = z;
    } else {
        const int u = t - 164096;
        const int row = u / 6, c = u - row * 6;      // row in [0,128)
        const int hh = row >> 4, m = 2048 + (row & 15);
        *(int4*)&Qb[((size_t)hh * QROWS + m) * 64 + c * 8] = z;
    }
}

// ---------------------------------------------------------------------------
// kvqg_gemm KV path: BK=128 (10 drain-steps, was 20). 16 chunks/row; full
// 4-bit both-sides XOR swizzle: LDS[row][c] = global[row][c ^ (row&15)].
// Staging: 4 rows per wave-issue (16 lanes/row); source chunk for lane =
// (lane&15) ^ ((it*4 + r4)&15) — per-issue compile-time constant.
// Read slot for k-half h = (h*4+lq) ^ lm (R&15 == lm). Conflict: 16 distinct
// chunks per 16-lane group -> 2 lanes per 4-bank group = free (m136).
// QG path: BK=64 swizzled-DMA (R8-verified machinery, 4 steps, was 8
// reg-staged). n-tile 64 + XCD grouping kept.
// ---------------------------------------------------------------------------
__global__ __launch_bounds__(256)
void kvqg_gemm(const u16* __restrict__ A, const u16* __restrict__ WT,
               u16* __restrict__ Kp, u16* __restrict__ V4,
               const u16* __restrict__ Ab, const u16* __restrict__ WT2,
               const float* __restrict__ bg, u16* __restrict__ Qb,
               float* __restrict__ gate, const int* __restrict__ kvwl) {
    __shared__ __align__(16) u16 As[128 * 128];  // 32 KB
    __shared__ __align__(16) u16 Bs[64 * 128];   // 16 KB
    const int tid = threadIdx.x;
    const int lane = tid & 63, wave = tid >> 6;
    const int wm64 = (wave >> 1) * 64, wn32 = (wave & 1) * 32;
    const int lm = lane & 15, lq = lane >> 4;

    if (blockIdx.x < 768) {
        // ---- K|V path: xcd = bx%8; same m-tile -> same xcd ----
        const int xcd = blockIdx.x & 7;
        const int rr = blockIdx.x >> 3;          // 0..95
        const int nti = rr % 12;
        const int mthi = rr / 12;                // 0..7
        const int e = kvwl[mthi * 8 + xcd];
        if (e < 0) return;
        const int m0 = e;
        const int n0 = nti * 64;

        floatx4 acc[4][2] = {};

        const int r4 = lane >> 4, ch = lane & 15;
        const u16* agB = &A[(size_t)(m0 + wave * 32 + r4) * D_SEQ];
        const u16* bgB = &WT[(size_t)(n0 + wave * 16 + r4) * D_SEQ];

        for (int k0 = 0; k0 < D_SEQ; k0 += 128) {
            __syncthreads();
            #pragma unroll
            for (int it = 0; it < 8; ++it) {
                const int cs = (ch ^ ((it * 4 + r4) & 15)) * 8;
                load_lds16(agB + (size_t)(it * 4) * D_SEQ + k0 + cs,
                           &As[(wave * 32 + it * 4) * 128]);
            }
            #pragma unroll
            for (int it = 0; it < 4; ++it) {
                const int cs = (ch ^ ((it * 4 + r4) & 15)) * 8;
                load_lds16(bgB + (size_t)(it * 4) * D_SEQ + k0 + cs,
                           &Bs[(wave * 16 + it * 4) * 128]);
            }
            __syncthreads();

            #pragma unroll
            for (int h = 0; h < 4; ++h) {
                const int sl = ((h * 4 + lq) ^ lm) * 8;
                short8 af[4], bf[2];
                #pragma unroll
                for (int i = 0; i < 4; ++i)
                    af[i] = *(const short8*)&As[(wm64 + i * 16 + lm) * 128 + sl];
                #pragma unroll
                for (int j = 0; j < 2; ++j)
                    bf[j] = *(const short8*)&Bs[(wn32 + j * 16 + lm) * 128 + sl];
                #pragma unroll
                for (int i = 0; i < 4; ++i)
                    #pragma unroll
                    for (int j = 0; j < 2; ++j)
                        acc[i][j] = __builtin_amdgcn_mfma_f32_16x16x32_bf16(
                            af[i], bf[j], acc[i][j], 0, 0, 0);
            }
        }

        #pragma unroll
        for (int i = 0; i < 4; ++i) {
            const int mrow = m0 + wm64 + i * 16 + lq * 4;   // b*1024+s, s%4==0
            const int bb = mrow >> 10, s = mrow & 1023;
            #pragma unroll
            for (int j = 0; j < 2; ++j) {
                const int n = n0 + wn32 + j * 16 + lm;
                if (n < HDH) {
                    const int hh = n / 48, dd = n - hh * 48;
                    u16* kp = &Kp[(((size_t)(bb * N_HEAD + hh)) * S_LEN + s) * 64 + dd];
                    kp[0]   = f2bf(acc[i][j][0]);
                    kp[64]  = f2bf(acc[i][j][1]);
                    kp[128] = f2bf(acc[i][j][2]);
                    kp[192] = f2bf(acc[i][j][3]);
                } else {
                    const int nv = n - HDH;
                    const int hh = nv / 48, dd = nv - hh * 48;
                    ushort4v pk;
                    pk[0] = f2bf(acc[i][j][0]); pk[1] = f2bf(acc[i][j][1]);
                    pk[2] = f2bf(acc[i][j][2]); pk[3] = f2bf(acc[i][j][3]);
                    *(ushort4v*)&V4[(((size_t)(bb * N_HEAD + hh)) * (S_LEN / 4) + (s >> 2)) * 192 + dd * 4] = pk;
                }
            }
        }
        return;
    }

    // ---- Q|gate path: BK=64 swizzled-DMA (R8 machinery), 4 steps ----
    {
        const int u = blockIdx.x - 768;          // 0..191
        const int xcd = u & 7;
        const int rr = u >> 3;                   // 0..23
        const int nti = rr % 12;
        const int mthi = rr / 12;                // 0..1
        const int m0 = (mthi * 8 + xcd) * 128;
        const int n0 = nti * 64;

        floatx4 acc[4][2] = {};

        const int r8 = lane >> 3;
        const int csw = ((lane & 7) ^ (r8 & 7)) * 8;
        const int s0 = (lq ^ (lm & 7)) * 8;
        const int s1 = s0 ^ 32;

        const u16* ag  = &Ab[(size_t)(m0 + wave * 32 + r8) * D + csw];
        const u16* bgp = &WT2[(size_t)(n0 + wave * 16 + r8) * D + csw];

        for (int k0 = 0; k0 < D; k0 += 64) {
            __syncthreads();
            #pragma unroll
            for (int it = 0; it < 4; ++it)
                load_lds16(ag + (size_t)(it * 8) * D + k0,
                           &As[(wave * 32 + it * 8) * 64]);
            #pragma unroll
            for (int it = 0; it < 2; ++it)
                load_lds16(bgp + (size_t)(it * 8) * D + k0,
                           &Bs[(wave * 16 + it * 8) * 64]);
            __syncthreads();

            short8 af[4][2], bfv[2][2];
            #pragma unroll
            for (int i = 0; i < 4; ++i) {
                const int R = wm64 + i * 16 + lm;
                af[i][0] = *(const short8*)&As[R * 64 + s0];
                af[i][1] = *(const short8*)&As[R * 64 + s1];
            }
            #pragma unroll
            for (int j = 0; j < 2; ++j) {
                const int R = wn32 + j * 16 + lm;
                bfv[j][0] = *(const short8*)&Bs[R * 64 + s0];
                bfv[j][1] = *(const short8*)&Bs[R * 64 + s1];
            }
            #pragma unroll
            for (int h = 0; h < 2; ++h)
                #pragma unroll
                for (int i = 0; i < 4; ++i)
                    #pragma unroll
                    for (int j = 0; j < 2; ++j)
                        acc[i][j] = __builtin_amdgcn_mfma_f32_16x16x32_bf16(
                            af[i][h], bfv[j][h], acc[i][j], 0, 0, 0);
        }

        #pragma unroll
        for (int i = 0; i < 4; ++i) {
            const int mb = m0 + wm64 + i * 16 + lq * 4;
            #pragma unroll
            for (int j = 0; j < 2; ++j) {
                const int n = n0 + wn32 + j * 16 + lm;
                #pragma unroll
                for (int r = 0; r < 4; ++r) {
                    const int m = mb + r;
                    const float v = acc[i][j][r];
                    if (n < HDH) {
                        const int hh = n / 48, dd = n - hh * 48;
                        Qb[((size_t)hh * QROWS + m) * 64 + dd] = f2bf(v * QSCALE);
                    } else {
                        const int ng = n - HDH;
                        gate[(size_t)m * HDH + ng] = 1.f / (1.f + __expf(-(v + bg[ng])));
                    }
                }
            }
        }
    }
}

// ---------------------------------------------------------------------------
// back-projection — BK=128 swizzled-DMA (3 drain-steps, was 6). Same 4-bit
// XOR machinery as the KV path, row stride HDH.
// ---------------------------------------------------------------------------
__global__ __launch_bounds__(256)
void back_gemm(const u16* __restrict__ Ab, const u16* __restrict__ Bt,
               const float* __restrict__ bias, const float* __restrict__ resid,
               float* __restrict__ C) {
    __shared__ __align__(16) u16 As[128 * 128];
    __shared__ __align__(16) u16 Bs[64 * 128];
    const int tid = threadIdx.x;
    const int lane = tid & 63, wave = tid >> 6;
    const int wm = (wave >> 1) * 64, wn = (wave & 1) * 32;
    const int m0 = blockIdx.y * 128, n0 = blockIdx.x * 64;
    const int lm = lane & 15, lq = lane >> 4;
    const int r4 = lane >> 4, ch = lane & 15;

    floatx4 acc[4][2] = {};

    const u16* agB = &Ab[(size_t)(m0 + wave * 32 + r4) * HDH];
    const u16* bgB = &Bt[(size_t)(n0 + wave * 16 + r4) * HDH];

    for (int k0 = 0; k0 < HDH; k0 += 128) {
        __syncthreads();
        #pragma unroll
        for (int it = 0; it < 8; ++it) {
            const int cs = (ch ^ ((it * 4 + r4) & 15)) * 8;
            load_lds16(agB + (size_t)(it * 4) * HDH + k0 + cs,
                       &As[(wave * 32 + it * 4) * 128]);
        }
        #pragma unroll
        for (int it = 0; it < 4; ++it) {
            const int cs = (ch ^ ((it * 4 + r4) & 15)) * 8;
            load_lds16(bgB + (size_t)(it * 4) * HDH + k0 + cs,
                       &Bs[(wave * 16 + it * 4) * 128]);
        }
        __syncthreads();

        #pragma unroll
        for (int h = 0; h < 4; ++h) {
            const int sl = ((h * 4 + lq) ^ lm) * 8;
            short8 af[4], bf[2];
            #pragma unroll
            for (int i = 0; i < 4; ++i)
                af[i] = *(const short8*)&As[(wm + i * 16 + lm) * 128 + sl];
            #pragma unroll
            for (int j = 0; j < 2; ++j)
                bf[j] = *(const short8*)&Bs[(wn + j * 16 + lm) * 128 + sl];
            #pragma unroll
            for (int i = 0; i < 4; ++i)
                #pragma unroll
                for (int j = 0; j < 2; ++j)
                    acc[i][j] = __builtin_amdgcn_mfma_f32_16x16x32_bf16(
                        af[i], bf[j], acc[i][j], 0, 0, 0);
        }
    }

    #pragma unroll
    for (int i = 0; i < 4; ++i) {
        const int mb = m0 + wm + i * 16 + lq * 4;
        #pragma unroll
        for (int j = 0; j < 2; ++j) {
            const int n = n0 + wn + j * 16 + lm;
            #pragma unroll
            for (int r = 0; r < 4; ++r) {
                const int m = mb + r;
                C[(size_t)m * D + n] = acc[i][j][r] + bias[n] + resid[(size_t)m * D + n];
            }
        }
    }
}

// ---------------------------------------------------------------------------
// MFMA flash attention, single split, fused inv(L)*gate epilogue — unchanged.
// ---------------------------------------------------------------------------
struct Pref {
    short8 k0, k1;
    short4v v0, v1, v2;
};

__device__ __forceinline__ Pref ldpref(const u16* kbase, const u16* vbase,
                                       int s, int lm, int lq) {
    Pref p;
    const u16* kr = &kbase[(size_t)(s + lm) * 64];
    p.k0 = *(const short8*)&kr[lq * 8];
    p.k1 = *(const short8*)&kr[32 + lq * 8];
    const size_t vo = (size_t)((s >> 2) + lq) * 192;
    p.v0 = *(const short4v*)&vbase[vo];
    p.v1 = *(const short4v*)&vbase[vo + 64];
    p.v2 = *(const short4v*)&vbase[vo + 128];
    return p;
}

__global__ __launch_bounds__(256)
void attn_mfma(const u16* __restrict__ Qb, const u16* __restrict__ Kp,
               const u16* __restrict__ V4, const int* __restrict__ scnt,
               const int* __restrict__ ranges, const int* __restrict__ wl,
               const float* __restrict__ gate, u16* __restrict__ gfeatb) {
    const int e = wl[blockIdx.x];
    if (e < 0) return;
    const int b = e >> 16, n0 = e & 0xffff;
    const int h = blockIdx.y;
    const int nend = ranges[b + 1];
    const int NT = min(16, nend - n0);

    const int tid = threadIdx.x;
    const int wave = tid >> 6, lane = tid & 63;
    const int lm = lane & 15, lq = lane >> 4;
    const int bh = b * N_HEAD + h;

    const u16* qrow = &Qb[((size_t)h * QROWS + n0 + lm) * 64];
    const short8 qf0 = *(const short8*)&qrow[lq * 8];
    const short8 qf1 = *(const short8*)&qrow[32 + lq * 8];

    const u16* kbase = &Kp[(size_t)bh * S_LEN * 64];
    const u16* vbase = &V4[(size_t)bh * (S_LEN / 4) * 192 + (size_t)lm * 4];

    const int cnt = scnt[b];
    const int T = (cnt + 15) >> 4;           // total 16-row s-tiles
    const int j = wave;                      // worker id: tiles j, j+4, j+8, ...
    const int nt = (j < T) ? (((T - 1 - j) >> 2) + 1) : 0;

    float l_i = 0.f;
    floatx4 acc0 = {}, acc1 = {}, acc2 = {};

    Pref pA, pB;
    if (nt > 0) pA = ldpref(kbase, vbase, j * 16, lm, lq);
    if (nt > 1) pB = ldpref(kbase, vbase, (j + 4) * 16, lm, lq);

    int t = 0;
    auto step = [&](Pref& P) {
        const int s0 = (j + t * 4) * 16;
        floatx4 st = {};
        st = __builtin_amdgcn_mfma_f32_16x16x32_bf16(P.k0, qf0, st, 0, 0, 0);
        st = __builtin_amdgcn_mfma_f32_16x16x32_bf16(P.k1, qf1, st, 0, 0, 0);
        const short4v v0 = P.v0, v1 = P.v1, v2 = P.v2;
        if (t + 2 < nt) P = ldpref(kbase, vbase, (j + (t + 2) * 4) * 16, lm, lq);

        const int rem = cnt - s0 - lq * 4;     // valid rows from this lane's group
        const float p0 = rem > 0 ? exp2f(st[0]) : 0.f;
        const float p1 = rem > 1 ? exp2f(st[1]) : 0.f;
        const float p2 = rem > 2 ? exp2f(st[2]) : 0.f;
        const float p3 = rem > 3 ? exp2f(st[3]) : 0.f;
        l_i += (p0 + p1) + (p2 + p3);

        union { __hip_bfloat162 h2[2]; short4v v; } pu;
        pu.h2[0] = __float22bfloat162_rn(make_float2(p0, p1));
        pu.h2[1] = __float22bfloat162_rn(make_float2(p2, p3));

        acc0 = __builtin_amdgcn_mfma_f32_16x16x16bf16_1k(v0, pu.v, acc0, 0, 0, 0);
        acc1 = __builtin_amdgcn_mfma_f32_16x16x16bf16_1k(v1, pu.v, acc1, 0, 0, 0);
        acc2 = __builtin_amdgcn_mfma_f32_16x16x16bf16_1k(v2, pu.v, acc2, 0, 0, 0);
        ++t;
    };
    while (t < nt) {
        step(pA);
        if (t < nt) step(pB);
    }

    l_i += __shfl_xor(l_i, 16);
    l_i += __shfl_xor(l_i, 32);

    __shared__ float sl[4][64];
    __shared__ float sacc[4][3][4][64];
    sl[wave][lane] = l_i;
    #pragma unroll
    for (int r = 0; r < 4; ++r) {
        sacc[wave][0][r][lane] = acc0[r];
        sacc[wave][1][r][lane] = acc1[r];
        sacc[wave][2][r][lane] = acc2[r];
    }
    __syncthreads();
    if (wave < 3 && lm < NT) {
        const int dt = wave;
        const float L = sl[0][lane] + sl[1][lane] + sl[2][lane] + sl[3][lane];
        const float inv = 1.f / (L + 1e-9f);
        const size_t o = (size_t)(n0 + lm) * HDH + h * 48 + dt * 16 + lq * 4;
        const float4 g = *(const float4*)&gate[o];
        float4 ov;
        ov.x = sacc[0][dt][0][lane] + sacc[1][dt][0][lane] +
               sacc[2][dt][0][lane] + sacc[3][dt][0][lane];
        ov.y = sacc[0][dt][1][lane] + sacc[1][dt][1][lane] +
               sacc[2][dt][1][lane] + sacc[3][dt][1][lane];
        ov.z = sacc[0][dt][2][lane] + sacc[1][dt][2][lane] +
               sacc[2][dt][2][lane] + sacc[3][dt][2][lane];
        ov.w = sacc[0][dt][3][lane] + sacc[1][dt][3][lane] +
               sacc[2][dt][3][lane] + sacc[3][dt][3][lane];
        union { __hip_bfloat162 h2[2]; ushort4v v; } r2;
        r2.h2[0] = __float22bfloat162_rn(make_float2(ov.x * inv * g.x,
                                                     ov.y * inv * g.y));
        r2.h2[1] = __float22bfloat162_rn(make_float2(ov.z * inv * g.z,
                                                     ov.w * inv * g.w));
        *(ushort4v*)&gfeatb[o] = r2.v;
    }
}

// ---------------------------------------------------------------------------
extern "C" void kernel_launch(void* const* d_in, const int* in_sizes, int n_in,
                              void* d_out, int out_size, void* d_ws, size_t ws_size,
                              hipStream_t stream) {
    const float* node  = (const float*)d_in[0];
    const float* emb   = (const float*)d_in[1];
    const int*   mask  = (const int*)d_in[2];
    const int*   batch = (const int*)d_in[3];
    const float* ln_g  = (const float*)d_in[4];
    const float* ln_b  = (const float*)d_in[5];
    const float* Wq    = (const float*)d_in[6];
    const float* Wk    = (const float*)d_in[7];
    const float* Wv    = (const float*)d_in[8];
    const float* Wg    = (const float*)d_in[9];
    const float* bg    = (const float*)d_in[10];
    const float* Wback = (const float*)d_in[11];
    const float* bback = (const float*)d_in[12];
    float* out = (float*)d_out;

    float* ws    = (float*)d_ws;
    float* gate  = ws;                                     // 2048*384 f32
    float* Pacc  = gate + (size_t)N_NODE * HDH;            // (unused now)
    float* Pl    = Pacc + (size_t)2 * N_NODE * HDH;        // (unused now)
    u16*   gfeatb = (u16*)(Pl + (size_t)2 * N_NODE * N_HEAD);  // 2048*384 u16
    u16*   yb    = gfeatb + (size_t)N_NODE * HDH;          // 2048*256 u16
    u16*   WT    = yb + (size_t)N_NODE * D;                // 768*1280 u16
    u16*   WT2   = WT + (size_t)KVN * D_SEQ;               // 768*256 u16
    u16*   WbT   = WT2 + (size_t)QGN * D;                  // 256*384 u16
    u16*   Qb    = WbT + (size_t)D * HDH;                  // 8*2064*64 u16
    u16*   Kp    = Qb + (size_t)N_HEAD * QROWS * 64;       // 64*1024*64 u16
    u16*   V4    = Kp + (size_t)B_GRAPH * N_HEAD * S_LEN * 64;  // 64*256*192 u16
    u16*   embb  = V4 + (size_t)B_GRAPH * N_HEAD * (S_LEN / 4) * 192; // 8192*1280
    int*   ranges = (int*)(embb + (size_t)B_GRAPH * S_LEN * D_SEQ);
    int*   wl    = ranges + 16;
    int*   kvwl  = wl + NWL;
    int*   scnt  = kvwl + 64;

    // 4 launches total
    prep<<<4321 + PAD_T / 256, 256, 0, stream>>>(
        emb, embb, node, ln_g, ln_b, yb, Wk, Wv, Wq, Wg, Wback,
        WT, WT2, WbT, batch, mask, ranges, wl, kvwl, scnt, Kp, Qb);
    kvqg_gemm<<<960, 256, 0, stream>>>(embb, WT, Kp, V4, yb, WT2, bg, Qb, gate, kvwl);
    attn_mfma<<<dim3(NWL, N_HEAD), 256, 0, stream>>>(
        Qb, Kp, V4, scnt, ranges, wl, gate, gfeatb);
    back_gemm<<<dim3(D / 64, N_NODE / 128), 256, 0, stream>>>(
        gfeatb, WbT, bback, node, out);
}

// Round 12
// 153.447 us; speedup vs baseline: 1.0123x; 1.0123x over previous
//
#include <hip/hip_runtime.h>
#include <hip/hip_bf16.h>
#include <math.h>

#define D 256
#define D_SEQ 1280
#define D_HEAD 48
#define N_HEAD 8
#define HDH 384        // N_HEAD * D_HEAD
#define N_NODE 2048
#define B_GRAPH 8
#define S_LEN 1024
#define LN_EPS 1e-5f
#define QSCALE (0.14433756729740643f * 1.4426950408889634f)  // 1/sqrt(48)*log2(e)
#define KVN 768
#define QGN 768
#define QROWS (N_NODE + 16)              // padded Q rows per head
#define TPG 40         // max 16-node tiles per graph
#define NWL (TPG * 8)  // strided worklist: wl[i*8+b]
#define PAD_T 164864

typedef unsigned short u16;
typedef __attribute__((ext_vector_type(8))) short short8;
typedef __attribute__((ext_vector_type(4))) short short4v;
typedef __attribute__((ext_vector_type(4))) unsigned short ushort4v;
typedef __attribute__((ext_vector_type(4))) float floatx4;

__device__ __forceinline__ u16 f2bf(float f) {
    unsigned int x = __float_as_uint(f);
    x += 0x7fff + ((x >> 16) & 1);      // RNE to bf16
    return (u16)(x >> 16);
}

// async 16B-per-lane global->LDS DMA (wave-uniform LDS base + lane*16B)
__device__ __forceinline__ void load_lds16(const u16* g, u16* lds) {
    __builtin_amdgcn_global_load_lds(
        (const __attribute__((address_space(1))) unsigned int*)g,
        (__attribute__((address_space(3))) unsigned int*)lds, 16, 0, 0);
}

// ---------------------------------------------------------------------------
// prep: R8-proven form.
// ---------------------------------------------------------------------------
__global__ __launch_bounds__(256)
void prep(const float* __restrict__ emb, u16* __restrict__ embb,
          const float* __restrict__ node, const float* __restrict__ ln_g,
          const float* __restrict__ ln_b, u16* __restrict__ yb,
          const float* __restrict__ Wk, const float* __restrict__ Wv,
          const float* __restrict__ Wq, const float* __restrict__ Wg,
          const float* __restrict__ Wback,
          u16* __restrict__ WT, u16* __restrict__ WT2, u16* __restrict__ WbT,
          const int* __restrict__ batch, const int* __restrict__ mask,
          int* __restrict__ ranges, int* __restrict__ wl,
          int* __restrict__ kvwl, int* __restrict__ scnt,
          u16* __restrict__ Kp, u16* __restrict__ Qb) {
    const int bx = blockIdx.x;
    const int tid = threadIdx.x;
    if (bx < 1024) {
        // ---- mask-compacted conversion: 8 rows/block, 32 lanes/row ----
        const int b = bx >> 7, chunk = bx & 127;
        __shared__ unsigned long long words[16];
        __shared__ int wpre[17];
        #pragma unroll
        for (int c = 0; c < 4; ++c) {
            const int s = c * 256 + tid;
            const unsigned long long bal = __ballot(mask[b * S_LEN + s] != 0);
            if ((tid & 63) == 0) words[c * 4 + (tid >> 6)] = bal;
        }
        __syncthreads();
        if (tid == 0) {
            int a = 0;
            #pragma unroll
            for (int w = 0; w < 16; ++w) { wpre[w] = a; a += __popcll(words[w]); }
            wpre[16] = a;
        }
        __syncthreads();
        const int cnt = wpre[16];
        const int ce = (cnt + 127) & ~127;        // ceil128
        const int r = chunk * 8 + (tid >> 5);     // orig row
        const int sub = tid & 31;
        const unsigned long long w = words[r >> 6];
        const bool on = (w >> (r & 63)) & 1ull;
        if (on) {
            const int rank = wpre[r >> 6] +
                __popcll(w & ((1ull << (r & 63)) - 1ull));
            const float* src = &emb[((size_t)b * S_LEN + r) * D_SEQ];
            u16* dst = &embb[((size_t)b * S_LEN + rank) * D_SEQ];
            #pragma unroll
            for (int it = 0; it < 5; ++it) {
                const int off = it * 256 + sub * 8;
                const float4 a = *(const float4*)&src[off];
                const float4 b4 = *(const float4*)&src[off + 4];
                union { u16 u[8]; int4 v; } p;
                p.u[0]=f2bf(a.x); p.u[1]=f2bf(a.y); p.u[2]=f2bf(a.z); p.u[3]=f2bf(a.w);
                p.u[4]=f2bf(b4.x); p.u[5]=f2bf(b4.y); p.u[6]=f2bf(b4.z); p.u[7]=f2bf(b4.w);
                *(int4*)&dst[off] = p.v;
            }
        }
        const int c2 = chunk * 8 + (tid >> 5);
        if (c2 >= cnt && c2 < ce) {
            u16* dst = &embb[((size_t)b * S_LEN + c2) * D_SEQ];
            const int4 z = {0, 0, 0, 0};
            #pragma unroll
            for (int it = 0; it < 5; ++it)
                *(int4*)&dst[it * 256 + sub * 8] = z;
        }
        return;
    }
    if (bx < 3072) {
        const int n = bx - 1024, t = tid;
        float x = node[n * D + t];
        float s = x, sq = x * x;
        #pragma unroll
        for (int o = 32; o > 0; o >>= 1) {
            s  += __shfl_down(s, o);
            sq += __shfl_down(sq, o);
        }
        __shared__ float ss[4], sqs[4];
        if ((t & 63) == 0) { ss[t >> 6] = s; sqs[t >> 6] = sq; }
        __syncthreads();
        float S  = ss[0] + ss[1] + ss[2] + ss[3];
        float SQ = sqs[0] + sqs[1] + sqs[2] + sqs[3];
        float mu  = S * (1.f / D);
        float var = SQ * (1.f / D) - mu * mu;
        float inv = rsqrtf(var + LN_EPS);
        yb[n * D + t] = f2bf((x - mu) * inv * ln_g[t] + ln_b[t]);
        return;
    }
    if (bx < 4320) {
        int u = bx - 3072;
        const float* W; u16* WTo; int K, kx, ny, Ncols;
        if (u < 480)      { W = Wk;    WTo = WT;                       K = D_SEQ; Ncols = HDH; kx = u % 40; ny = u / 40; }
        else if (u < 960) { u -= 480;  W = Wv; WTo = WT + (size_t)HDH * D_SEQ; K = D_SEQ; Ncols = HDH; kx = u % 40; ny = u / 40; }
        else if (u < 1056){ u -= 960;  W = Wq; WTo = WT2;              K = D;   Ncols = HDH; kx = u % 8;  ny = u / 8; }
        else if (u < 1152){ u -= 1056; W = Wg; WTo = WT2 + (size_t)HDH * D; K = D; Ncols = HDH; kx = u % 8; ny = u / 8; }
        else              { u -= 1152; W = Wback; WTo = WbT;           K = HDH; Ncols = D;   kx = u % 12; ny = u / 12; }
        const int k0 = kx * 32, n0 = ny * 32;
        __shared__ float tile[32][33];
        const int tx = tid & 31, ty = tid >> 5;
        #pragma unroll
        for (int i = 0; i < 32; i += 8)
            tile[ty + i][tx] = W[(size_t)(k0 + ty + i) * Ncols + n0 + tx];
        __syncthreads();
        #pragma unroll
        for (int i = 0; i < 32; i += 8)
            WTo[(size_t)(n0 + ty + i) * K + k0 + tx] = f2bf(tile[tx][ty + i]);
        return;
    }
    if (bx == 4320) {
        const int t = tid;
        __shared__ int msum[8][32];
        __shared__ int mcnt[8];
        const int g = t >> 5, ii = t & 31;
        int p = 0;
        #pragma unroll
        for (int k = 0; k < 32; ++k) p += mask[g * S_LEN + k * 32 + ii];
        msum[g][ii] = p;
        if (t <= B_GRAPH) {
            int lo = 0, hi = N_NODE;
            while (lo < hi) {
                int mid = (lo + hi) >> 1;
                if (batch[mid] < t) lo = mid + 1; else hi = mid;
            }
            ranges[t] = lo;
        }
        __syncthreads();
        if (t < 8) {
            int s = 0;
            #pragma unroll
            for (int k = 0; k < 32; ++k) s += msum[t][k];
            mcnt[t] = s;
            scnt[t] = s;
        }
        __syncthreads();
        if (t < B_GRAPH) {
            const int s = ranges[t];
            const int ntile = (ranges[t + 1] - s + 15) >> 4;
            for (int i = 0; i < TPG; ++i)
                wl[i * 8 + t] = (i < ntile) ? ((t << 16) | (s + i * 16)) : -1;
            const int tc = (mcnt[t] + 127) >> 7;   // KV m-tiles for this graph
            for (int i = 0; i < 8; ++i)
                kvwl[i * 8 + t] = (i < tc) ? (t * S_LEN + i * 128) : -1;
        }
        return;
    }
    const int t = (bx - 4321) * 256 + tid;
    const int4 z = {0, 0, 0, 0};
    if (t < 131072) {
        const int row = t >> 1, half = t & 1;
        *(int4*)&Kp[(size_t)row * 64 + 48 + half * 8] = z;
    } else if (t < 164096) {
        const int u = t - 131072;
        const int row = u >> 1, half = u & 1;
        *(int4*)&Qb[(size_t)row * 64 + 48 + half * 8] = z;
    } else {
        const int u = t - 164096;
        const int row = u / 6, c = u - row * 6;      // row in [0,128)
        const int hh = row >> 4, m = 2048 + (row & 15);
        *(int4*)&Qb[((size_t)hh * QROWS + m) * 64 + c * 8] = z;
    }
}

// ---------------------------------------------------------------------------
// kvqg_gemm KV path: BK=64 (20 drain-steps) + both-sides XOR swizzle:
// LDS[row][chunk c] = global[row][c^(row&7)] via pre-swizzled per-lane
// SOURCE (DMA dest stays linear); ds_read XORs the chunk back.
// n-tile 64 + XCD grouping. QG path: BK=32 reg-staged (hidden under KV).
// R8-proven: 154.5 us total.
// ---------------------------------------------------------------------------
__global__ __launch_bounds__(256)
void kvqg_gemm(const u16* __restrict__ A, const u16* __restrict__ WT,
               u16* __restrict__ Kp, u16* __restrict__ V4,
               const u16* __restrict__ Ab, const u16* __restrict__ WT2,
               const float* __restrict__ bg, u16* __restrict__ Qb,
               float* __restrict__ gate, const int* __restrict__ kvwl) {
    __shared__ __align__(16) u16 As[128 * 64];   // 16 KB
    __shared__ __align__(16) u16 Bs[64 * 64];    // 8 KB
    const int tid = threadIdx.x;
    const int lane = tid & 63, wave = tid >> 6;
    const int wm64 = (wave >> 1) * 64, wn32 = (wave & 1) * 32;
    const int lm = lane & 15, lq = lane >> 4;
    const int r8 = lane >> 3;                        // staging row within 8-group
    const int csw = ((lane & 7) ^ (r8 & 7)) * 8;     // pre-swizzled source chunk
    const int s0 = (lq ^ (lm & 7)) * 8;              // frag read slot, k-half 0
    const int s1 = s0 ^ 32;                          // k-half 1

    if (blockIdx.x < 768) {
        // ---- K|V path: xcd = bx%8; same m-tile -> same xcd ----
        const int xcd = blockIdx.x & 7;
        const int rr = blockIdx.x >> 3;          // 0..95
        const int nti = rr % 12;
        const int mthi = rr / 12;                // 0..7
        const int e = kvwl[mthi * 8 + xcd];
        if (e < 0) return;
        const int m0 = e;
        const int n0 = nti * 64;

        floatx4 acc[4][2] = {};

        const u16* ag  = &A[(size_t)(m0 + wave * 32 + r8) * D_SEQ + csw];
        const u16* bgp = &WT[(size_t)(n0 + wave * 16 + r8) * D_SEQ + csw];

        for (int k0 = 0; k0 < D_SEQ; k0 += 64) {
            __syncthreads();
            #pragma unroll
            for (int it = 0; it < 4; ++it)
                load_lds16(ag + (size_t)(it * 8) * D_SEQ + k0,
                           &As[(wave * 32 + it * 8) * 64]);
            #pragma unroll
            for (int it = 0; it < 2; ++it)
                load_lds16(bgp + (size_t)(it * 8) * D_SEQ + k0,
                           &Bs[(wave * 16 + it * 8) * 64]);
            __syncthreads();

            short8 af[4][2], bfv[2][2];
            #pragma unroll
            for (int i = 0; i < 4; ++i) {
                const int R = wm64 + i * 16 + lm;
                af[i][0] = *(const short8*)&As[R * 64 + s0];
                af[i][1] = *(const short8*)&As[R * 64 + s1];
            }
            #pragma unroll
            for (int j = 0; j < 2; ++j) {
                const int R = wn32 + j * 16 + lm;
                bfv[j][0] = *(const short8*)&Bs[R * 64 + s0];
                bfv[j][1] = *(const short8*)&Bs[R * 64 + s1];
            }
            #pragma unroll
            for (int h = 0; h < 2; ++h)
                #pragma unroll
                for (int i = 0; i < 4; ++i)
                    #pragma unroll
                    for (int j = 0; j < 2; ++j)
                        acc[i][j] = __builtin_amdgcn_mfma_f32_16x16x32_bf16(
                            af[i][h], bfv[j][h], acc[i][j], 0, 0, 0);
        }

        #pragma unroll
        for (int i = 0; i < 4; ++i) {
            const int mrow = m0 + wm64 + i * 16 + lq * 4;   // b*1024+s, s%4==0
            const int bb = mrow >> 10, s = mrow & 1023;
            #pragma unroll
            for (int j = 0; j < 2; ++j) {
                const int n = n0 + wn32 + j * 16 + lm;
                if (n < HDH) {
                    const int hh = n / 48, dd = n - hh * 48;
                    u16* kp = &Kp[(((size_t)(bb * N_HEAD + hh)) * S_LEN + s) * 64 + dd];
                    kp[0]   = f2bf(acc[i][j][0]);
                    kp[64]  = f2bf(acc[i][j][1]);
                    kp[128] = f2bf(acc[i][j][2]);
                    kp[192] = f2bf(acc[i][j][3]);
                } else {
                    const int nv = n - HDH;
                    const int hh = nv / 48, dd = nv - hh * 48;
                    ushort4v pk;
                    pk[0] = f2bf(acc[i][j][0]); pk[1] = f2bf(acc[i][j][1]);
                    pk[2] = f2bf(acc[i][j][2]); pk[3] = f2bf(acc[i][j][3]);
                    *(ushort4v*)&V4[(((size_t)(bb * N_HEAD + hh)) * (S_LEN / 4) + (s >> 2)) * 192 + dd * 4] = pk;
                }
            }
        }
        return;
    }

    // ---- Q|gate path (n-tile 64, XCD-grouped, BK=32 reg-staged) ----
    {
        const int u = blockIdx.x - 768;          // 0..191
        const int xcd = u & 7;
        const int rr = u >> 3;                   // 0..23
        const int nti = rr % 12;
        const int mthi = rr / 12;                // 0..1
        const int m0 = (mthi * 8 + xcd) * 128;
        const int n0 = nti * 64;

        floatx4 acc[4][2] = {};
        const int sr = tid >> 2;
        const int sc = (tid & 3) * 8;

        for (int k0 = 0; k0 < D; k0 += 32) {
            const int4 a0 = *(const int4*)&Ab[(size_t)(m0 + sr) * D + k0 + sc];
            const int4 a1 = *(const int4*)&Ab[(size_t)(m0 + sr + 64) * D + k0 + sc];
            const int4 b0 = *(const int4*)&WT2[(size_t)(n0 + sr) * D + k0 + sc];
            __syncthreads();
            *(int4*)&As[sr * 32 + sc] = a0;
            *(int4*)&As[(sr + 64) * 32 + sc] = a1;
            *(int4*)&Bs[sr * 32 + sc] = b0;
            __syncthreads();

            short8 af[4], bfr[2];
            #pragma unroll
            for (int i = 0; i < 4; ++i)
                af[i] = *(const short8*)&As[(wm64 + i * 16 + lm) * 32 + lq * 8];
            #pragma unroll
            for (int j = 0; j < 2; ++j)
                bfr[j] = *(const short8*)&Bs[(wn32 + j * 16 + lm) * 32 + lq * 8];
            #pragma unroll
            for (int i = 0; i < 4; ++i)
                #pragma unroll
                for (int j = 0; j < 2; ++j)
                    acc[i][j] = __builtin_amdgcn_mfma_f32_16x16x32_bf16(
                        af[i], bfr[j], acc[i][j], 0, 0, 0);
        }

        #pragma unroll
        for (int i = 0; i < 4; ++i) {
            const int mb = m0 + wm64 + i * 16 + lq * 4;
            #pragma unroll
            for (int j = 0; j < 2; ++j) {
                const int n = n0 + wn32 + j * 16 + lm;
                #pragma unroll
                for (int r = 0; r < 4; ++r) {
                    const int m = mb + r;
                    const float v = acc[i][j][r];
                    if (n < HDH) {
                        const int hh = n / 48, dd = n - hh * 48;
                        Qb[((size_t)hh * QROWS + m) * 64 + dd] = f2bf(v * QSCALE);
                    } else {
                        const int ng = n - HDH;
                        gate[(size_t)m * HDH + ng] = 1.f / (1.f + __expf(-(v + bg[ng])));
                    }
                }
            }
        }
    }
}

// ---------------------------------------------------------------------------
// back-projection — BK=64 swizzled-DMA pattern (6 steps). R8-proven.
// ---------------------------------------------------------------------------
__global__ __launch_bounds__(256)
void back_gemm(const u16* __restrict__ Ab, const u16* __restrict__ Bt,
               const float* __restrict__ bias, const float* __restrict__ resid,
               float* __restrict__ C) {
    __shared__ __align__(16) u16 As[128 * 64];
    __shared__ __align__(16) u16 Bs[64 * 64];
    const int tid = threadIdx.x;
    const int lane = tid & 63, wave = tid >> 6;
    const int wm = (wave >> 1) * 64, wn = (wave & 1) * 32;
    const int m0 = blockIdx.y * 128, n0 = blockIdx.x * 64;
    const int lm = lane & 15, lq = lane >> 4;
    const int r8 = lane >> 3;
    const int csw = ((lane & 7) ^ (r8 & 7)) * 8;
    const int s0 = (lq ^ (lm & 7)) * 8;
    const int s1 = s0 ^ 32;

    floatx4 acc[4][2] = {};

    const u16* ag  = &Ab[(size_t)(m0 + wave * 32 + r8) * HDH + csw];
    const u16* bgp = &Bt[(size_t)(n0 + wave * 16 + r8) * HDH + csw];

    for (int k0 = 0; k0 < HDH; k0 += 64) {
        __syncthreads();
        #pragma unroll
        for (int it = 0; it < 4; ++it)
            load_lds16(ag + (size_t)(it * 8) * HDH + k0,
                       &As[(wave * 32 + it * 8) * 64]);
        #pragma unroll
        for (int it = 0; it < 2; ++it)
            load_lds16(bgp + (size_t)(it * 8) * HDH + k0,
                       &Bs[(wave * 16 + it * 8) * 64]);
        __syncthreads();

        short8 af[4][2], bfv[2][2];
        #pragma unroll
        for (int i = 0; i < 4; ++i) {
            const int R = wm + i * 16 + lm;
            af[i][0] = *(const short8*)&As[R * 64 + s0];
            af[i][1] = *(const short8*)&As[R * 64 + s1];
        }
        #pragma unroll
        for (int j = 0; j < 2; ++j) {
            const int R = wn + j * 16 + lm;
            bfv[j][0] = *(const short8*)&Bs[R * 64 + s0];
            bfv[j][1] = *(const short8*)&Bs[R * 64 + s1];
        }
        #pragma unroll
        for (int h = 0; h < 2; ++h)
            #pragma unroll
            for (int i = 0; i < 4; ++i)
                #pragma unroll
                for (int j = 0; j < 2; ++j)
                    acc[i][j] = __builtin_amdgcn_mfma_f32_16x16x32_bf16(
                        af[i][h], bfv[j][h], acc[i][j], 0, 0, 0);
    }

    #pragma unroll
    for (int i = 0; i < 4; ++i) {
        const int mb = m0 + wm + i * 16 + lq * 4;
        #pragma unroll
        for (int j = 0; j < 2; ++j) {
            const int n = n0 + wn + j * 16 + lm;
            #pragma unroll
            for (int r = 0; r < 4; ++r) {
                const int m = mb + r;
                C[(size_t)m * D + n] = acc[i][j][r] + bias[n] + resid[(size_t)m * D + n];
            }
        }
    }
}

// ---------------------------------------------------------------------------
// MFMA flash attention, single split, fused inv(L)*gate epilogue — R8-proven.
// ---------------------------------------------------------------------------
struct Pref {
    short8 k0, k1;
    short4v v0, v1, v2;
};

__device__ __forceinline__ Pref ldpref(const u16* kbase, const u16* vbase,
                                       int s, int lm, int lq) {
    Pref p;
    const u16* kr = &kbase[(size_t)(s + lm) * 64];
    p.k0 = *(const short8*)&kr[lq * 8];
    p.k1 = *(const short8*)&kr[32 + lq * 8];
    const size_t vo = (size_t)((s >> 2) + lq) * 192;
    p.v0 = *(const short4v*)&vbase[vo];
    p.v1 = *(const short4v*)&vbase[vo + 64];
    p.v2 = *(const short4v*)&vbase[vo + 128];
    return p;
}

__global__ __launch_bounds__(256)
void attn_mfma(const u16* __restrict__ Qb, const u16* __restrict__ Kp,
               const u16* __restrict__ V4, const int* __restrict__ scnt,
               const int* __restrict__ ranges, const int* __restrict__ wl,
               const float* __restrict__ gate, u16* __restrict__ gfeatb) {
    const int e = wl[blockIdx.x];
    if (e < 0) return;
    const int b = e >> 16, n0 = e & 0xffff;
    const int h = blockIdx.y;
    const int nend = ranges[b + 1];
    const int NT = min(16, nend - n0);

    const int tid = threadIdx.x;
    const int wave = tid >> 6, lane = tid & 63;
    const int lm = lane & 15, lq = lane >> 4;
    const int bh = b * N_HEAD + h;

    const u16* qrow = &Qb[((size_t)h * QROWS + n0 + lm) * 64];
    const short8 qf0 = *(const short8*)&qrow[lq * 8];
    const short8 qf1 = *(const short8*)&qrow[32 + lq * 8];

    const u16* kbase = &Kp[(size_t)bh * S_LEN * 64];
    const u16* vbase = &V4[(size_t)bh * (S_LEN / 4) * 192 + (size_t)lm * 4];

    const int cnt = scnt[b];
    const int T = (cnt + 15) >> 4;           // total 16-row s-tiles
    const int j = wave;                      // worker id: tiles j, j+4, j+8, ...
    const int nt = (j < T) ? (((T - 1 - j) >> 2) + 1) : 0;

    float l_i = 0.f;
    floatx4 acc0 = {}, acc1 = {}, acc2 = {};

    Pref pA, pB;
    if (nt > 0) pA = ldpref(kbase, vbase, j * 16, lm, lq);
    if (nt > 1) pB = ldpref(kbase, vbase, (j + 4) * 16, lm, lq);

    int t = 0;
    auto step = [&](Pref& P) {
        const int s0 = (j + t * 4) * 16;
        floatx4 st = {};
        st = __builtin_amdgcn_mfma_f32_16x16x32_bf16(P.k0, qf0, st, 0, 0, 0);
        st = __builtin_amdgcn_mfma_f32_16x16x32_bf16(P.k1, qf1, st, 0, 0, 0);
        const short4v v0 = P.v0, v1 = P.v1, v2 = P.v2;
        if (t + 2 < nt) P = ldpref(kbase, vbase, (j + (t + 2) * 4) * 16, lm, lq);

        const int rem = cnt - s0 - lq * 4;     // valid rows from this lane's group
        const float p0 = rem > 0 ? exp2f(st[0]) : 0.f;
        const float p1 = rem > 1 ? exp2f(st[1]) : 0.f;
        const float p2 = rem > 2 ? exp2f(st[2]) : 0.f;
        const float p3 = rem > 3 ? exp2f(st[3]) : 0.f;
        l_i += (p0 + p1) + (p2 + p3);

        union { __hip_bfloat162 h2[2]; short4v v; } pu;
        pu.h2[0] = __float22bfloat162_rn(make_float2(p0, p1));
        pu.h2[1] = __float22bfloat162_rn(make_float2(p2, p3));

        acc0 = __builtin_amdgcn_mfma_f32_16x16x16bf16_1k(v0, pu.v, acc0, 0, 0, 0);
        acc1 = __builtin_amdgcn_mfma_f32_16x16x16bf16_1k(v1, pu.v, acc1, 0, 0, 0);
        acc2 = __builtin_amdgcn_mfma_f32_16x16x16bf16_1k(v2, pu.v, acc2, 0, 0, 0);
        ++t;
    };
    while (t < nt) {
        step(pA);
        if (t < nt) step(pB);
    }

    l_i += __shfl_xor(l_i, 16);
    l_i += __shfl_xor(l_i, 32);

    __shared__ float sl[4][64];
    __shared__ float sacc[4][3][4][64];
    sl[wave][lane] = l_i;
    #pragma unroll
    for (int r = 0; r < 4; ++r) {
        sacc[wave][0][r][lane] = acc0[r];
        sacc[wave][1][r][lane] = acc1[r];
        sacc[wave][2][r][lane] = acc2[r];
    }
    __syncthreads();
    if (wave < 3 && lm < NT) {
        const int dt = wave;
        const float L = sl[0][lane] + sl[1][lane] + sl[2][lane] + sl[3][lane];
        const float inv = 1.f / (L + 1e-9f);
        const size_t o = (size_t)(n0 + lm) * HDH + h * 48 + dt * 16 + lq * 4;
        const float4 g = *(const float4*)&gate[o];
        float4 ov;
        ov.x = sacc[0][dt][0][lane] + sacc[1][dt][0][lane] +
               sacc[2][dt][0][lane] + sacc[3][dt][0][lane];
        ov.y = sacc[0][dt][1][lane] + sacc[1][dt][1][lane] +
               sacc[2][dt][1][lane] + sacc[3][dt][1][lane];
        ov.z = sacc[0][dt][2][lane] + sacc[1][dt][2][lane] +
               sacc[2][dt][2][lane] + sacc[3][dt][2][lane];
        ov.w = sacc[0][dt][3][lane] + sacc[1][dt][3][lane] +
               sacc[2][dt][3][lane] + sacc[3][dt][3][lane];
        union { __hip_bfloat162 h2[2]; ushort4v v; } r2;
        r2.h2[0] = __float22bfloat162_rn(make_float2(ov.x * inv * g.x,
                                                     ov.y * inv * g.y));
        r2.h2[1] = __float22bfloat162_rn(make_float2(ov.z * inv * g.z,
                                                     ov.w * inv * g.w));
        *(ushort4v*)&gfeatb[o] = r2.v;
    }
}

// ---------------------------------------------------------------------------
extern "C" void kernel_launch(void* const* d_in, const int* in_sizes, int n_in,
                              void* d_out, int out_size, void* d_ws, size_t ws_size,
                              hipStream_t stream) {
    const float* node  = (const float*)d_in[0];
    const float* emb   = (const float*)d_in[1];
    const int*   mask  = (const int*)d_in[2];
    const int*   batch = (const int*)d_in[3];
    const float* ln_g  = (const float*)d_in[4];
    const float* ln_b  = (const float*)d_in[5];
    const float* Wq    = (const float*)d_in[6];
    const float* Wk    = (const float*)d_in[7];
    const float* Wv    = (const float*)d_in[8];
    const float* Wg    = (const float*)d_in[9];
    const float* bg    = (const float*)d_in[10];
    const float* Wback = (const float*)d_in[11];
    const float* bback = (const float*)d_in[12];
    float* out = (float*)d_out;

    float* ws    = (float*)d_ws;
    float* gate  = ws;                                     // 2048*384 f32
    float* Pacc  = gate + (size_t)N_NODE * HDH;            // (unused)
    float* Pl    = Pacc + (size_t)2 * N_NODE * HDH;        // (unused)
    u16*   gfeatb = (u16*)(Pl + (size_t)2 * N_NODE * N_HEAD);  // 2048*384 u16
    u16*   yb    = gfeatb + (size_t)N_NODE * HDH;          // 2048*256 u16
    u16*   WT    = yb + (size_t)N_NODE * D;                // 768*1280 u16
    u16*   WT2   = WT + (size_t)KVN * D_SEQ;               // 768*256 u16
    u16*   WbT   = WT2 + (size_t)QGN * D;                  // 256*384 u16
    u16*   Qb    = WbT + (size_t)D * HDH;                  // 8*2064*64 u16
    u16*   Kp    = Qb + (size_t)N_HEAD * QROWS * 64;       // 64*1024*64 u16
    u16*   V4    = Kp + (size_t)B_GRAPH * N_HEAD * S_LEN * 64;  // 64*256*192 u16
    u16*   embb  = V4 + (size_t)B_GRAPH * N_HEAD * (S_LEN / 4) * 192; // 8192*1280
    int*   ranges = (int*)(embb + (size_t)B_GRAPH * S_LEN * D_SEQ);
    int*   wl    = ranges + 16;
    int*   kvwl  = wl + NWL;
    int*   scnt  = kvwl + 64;

    // 4 launches total
    prep<<<4321 + PAD_T / 256, 256, 0, stream>>>(
        emb, embb, node, ln_g, ln_b, yb, Wk, Wv, Wq, Wg, Wback,
        WT, WT2, WbT, batch, mask, ranges, wl, kvwl, scnt, Kp, Qb);
    kvqg_gemm<<<960, 256, 0, stream>>>(embb, WT, Kp, V4, yb, WT2, bg, Qb, gate, kvwl);
    attn_mfma<<<dim3(NWL, N_HEAD), 256, 0, stream>>>(
        Qb, Kp, V4, scnt, ranges, wl, gate, gfeatb);
    back_gemm<<<dim3(D / 64, N_NODE / 128), 256, 0, stream>>>(
        gfeatb, WbT, bback, node, out);
}